// Round 3
// baseline (448.909 us; speedup 1.0000x reference)
//
#include <hip/hip_runtime.h>
#include <stdint.h>

// SelfAttention B=2,S=4096,E=1024,H=1024. f32 in, f32 out, bf16 MFMA inside.
// R10: m201 8-phase schedule, FIXED per m141/rule#18 analysis:
//   - removed sched_barrier(0) + pre-MFMA lgkmcnt(0) (they serialized
//     read-drain vs MFMA inside every phase; compiler now emits fine-grained
//     lgkmcnt and overlaps first MFMAs under the read tail).
//   - one asm lgkmcnt(0) AFTER the MFMA cluster (before end barrier):
//     preserves the cross-wave WAR guarantee (all waves' reads of a region
//     retired before any later-phase stage can overwrite it) and pins
//     ds_reads from sinking past the barrier ("memory" clobber).
//   - constexpr vmcnt/stage flags, peeled tail iteration (no per-phase
//     runtime branches on the wait path).
//   - XCD-aware bijective blockIdx swizzle (T1): B-panel L2-resident/XCD.
// R9: 8-phase + zero-conflict swizzle (verified 0 bank conflicts, but null
//     perf: sched_barrier(0) pinned the schedule = m141 failure mode).

typedef __bf16 bf16;
typedef __attribute__((ext_vector_type(4))) __bf16 bf16x4;
typedef __attribute__((ext_vector_type(8))) __bf16 bf16x8;
typedef __attribute__((ext_vector_type(4))) float f32x4;

__device__ __forceinline__ void g2l16(const void* g, void* l) {
  __builtin_amdgcn_global_load_lds(
      (const __attribute__((address_space(1))) uint32_t*)g,
      (__attribute__((address_space(3))) uint32_t*)l, 16, 0, 0);
}

template <int V> struct IC { static constexpr int value = V; };
template <bool V> struct BC { static constexpr bool value = V; };

template <int N> __device__ __forceinline__ void waitvm() {
  if constexpr (N == 6) asm volatile("s_waitcnt vmcnt(6)" ::: "memory");
  else if constexpr (N == 4) asm volatile("s_waitcnt vmcnt(4)" ::: "memory");
  else if constexpr (N == 0) asm volatile("s_waitcnt vmcnt(0)" ::: "memory");
}

// ---------------- f32 -> bf16 converters -----------------------------------
__global__ __launch_bounds__(256) void cvt_f32_bf16(
    const float* __restrict__ src, bf16* __restrict__ dst, int n) {
  const int i = (blockIdx.x * 256 + threadIdx.x) * 8;
  if (i >= n) return;
  f32x4 a = *(const f32x4*)(src + i);
  f32x4 b = *(const f32x4*)(src + i + 4);
  bf16x8 o;
#pragma unroll
  for (int e = 0; e < 4; ++e) { o[e] = (bf16)a[e]; o[4 + e] = (bf16)b[e]; }
  *(bf16x8*)(dst + i) = o;
}

__global__ __launch_bounds__(256) void cvt_w3(
    const float* __restrict__ Wq, const float* __restrict__ Wk,
    const float* __restrict__ Wv, bf16* __restrict__ dst) {
  const int i = (blockIdx.x * 256 + threadIdx.x) * 8;
  const int seg = i >> 20;
  const int off = i & 1048575;
  const float* src = (seg == 0) ? Wq : (seg == 1) ? Wk : Wv;
  f32x4 a = *(const f32x4*)(src + off);
  f32x4 b = *(const f32x4*)(src + off + 4);
  bf16x8 o;
#pragma unroll
  for (int e = 0; e < 4; ++e) { o[e] = (bf16)a[e]; o[4 + e] = (bf16)b[e]; }
  *(bf16x8*)(dst + i) = o;
}

// ======================= kloop256: BM=256 x BN=256, BK=64 ==================
// 8 waves 2M x 4N; wave tile 128x64. 4 phases per K-tile (phase q = M-quarter
// q, both k-halves, 16 MFMA). LDS buffer b: A[256][64] at b*32768, B at
// +16384 (elems). Chunk c of row r holds global chunk c^(r&7).
// Half-tiles: 0=B rows 0-127, 1=B rows 128-255 (B fully read at phase 0),
// 2=A rows {0-63,128-191} (read ph q0,q1), 3=A rows {64-127,192-255} (q2,q3).
// Steady iter (t0,t1): ph0:(t1,3) ph1:(t0+2,0) ph2:(t0+2,1)
//   ph3:(t0+2,2)+vmcnt(6) ph4:(t0+2,3) ph5:(t0+3,0) ph6:(t0+3,1)
//   ph7:(t0+3,2)+vmcnt(6).
// Each stage issues only after the end-barrier of the phase whose lgkmcnt(0)
// retired all waves' reads of that region; vmcnt sits BEFORE the tile-
// boundary barrier so the next tile's data is proven landed for ALL waves.
template <int NT>
__device__ __forceinline__ void kloop256(
    const bf16* __restrict__ Ag, const bf16* __restrict__ Bg, const int KA,
    const int KB, bf16* lds, f32x4 (&acc)[8][4]) {
  const int tid = threadIdx.x;
  const int lane = tid & 63, wave = tid >> 6;
  const int l15 = lane & 15, quad = lane >> 4;
  const int wrow = (wave >> 2) * 128;
  const int wcol = (wave & 3) * 64;
  const int srow = tid >> 3;                      // 0..63
  const int scol = ((tid & 7) ^ (srow & 7)) * 8;  // pre-swizzled source col
  const int swz = l15 & 7;

  auto stg = [&](int t, int h) {
    bf16* base = lds + (t & 1) * 32768;
    if (h == 0) {            // B rows 0-127
      const bf16* g = Bg + (size_t)srow * KB + t * 64 + scol;
      g2l16(g, base + 16384 + tid * 8);
      g2l16(g + (size_t)64 * KB, base + 16384 + tid * 8 + 4096);
    } else if (h == 1) {     // B rows 128-255
      const bf16* g = Bg + (size_t)(128 + srow) * KB + t * 64 + scol;
      g2l16(g, base + 24576 + tid * 8);
      g2l16(g + (size_t)64 * KB, base + 24576 + tid * 8 + 4096);
    } else if (h == 2) {     // A rows {0-63, 128-191}
      const bf16* g = Ag + (size_t)srow * KA + t * 64 + scol;
      g2l16(g, base + tid * 8);
      g2l16(g + (size_t)128 * KA, base + tid * 8 + 8192);
    } else {                 // A rows {64-127, 192-255}
      const bf16* g = Ag + (size_t)(64 + srow) * KA + t * 64 + scol;
      g2l16(g, base + 4096 + tid * 8);
      g2l16(g + (size_t)128 * KA, base + 4096 + tid * 8 + 8192);
    }
  };

  bf16x8 bq[2][4];
  auto phase = [&](int t, auto qc, int st, int sh, auto dsc, auto vmc) {
    constexpr int q = decltype(qc)::value;
    constexpr bool ds = decltype(dsc)::value;
    constexpr int vm = decltype(vmc)::value;
    bf16* base = lds + (t & 1) * 32768;
    bf16x8 af[2][2];
#pragma unroll
    for (int i = 0; i < 2; ++i)
#pragma unroll
      for (int ks = 0; ks < 2; ++ks)
        af[i][ks] = *(const bf16x8*)&base[
            (wrow + (2 * q + i) * 16 + l15) * 64 + ((ks * 4 + quad) ^ swz) * 8];
    if constexpr (q == 0) {
#pragma unroll
      for (int j = 0; j < 4; ++j)
#pragma unroll
        for (int ks = 0; ks < 2; ++ks)
          bq[ks][j] = *(const bf16x8*)&base[16384 +
              (wcol + j * 16 + l15) * 64 + ((ks * 4 + quad) ^ swz) * 8];
    }
    if constexpr (ds) stg(st, sh);
    __builtin_amdgcn_s_barrier();
    __builtin_amdgcn_s_setprio(1);
#pragma unroll
    for (int ks = 0; ks < 2; ++ks)
#pragma unroll
      for (int i = 0; i < 2; ++i)
#pragma unroll
        for (int j = 0; j < 4; ++j)
          acc[2 * q + i][j] = __builtin_amdgcn_mfma_f32_16x16x32_bf16(
              af[i][ks], bq[ks][j], acc[2 * q + i][j], 0, 0, 0);
    __builtin_amdgcn_s_setprio(0);
    // reads of this phase retired before end barrier (stage-landing safety);
    // also pins ds_reads from sinking past the barrier.
    asm volatile("s_waitcnt lgkmcnt(0)" ::: "memory");
    waitvm<vm>();
    __builtin_amdgcn_s_barrier();
  };

  // prologue: 7 half-tiles (14 loads); vmcnt(6) -> tile 0 fully landed.
  stg(0, 0); stg(0, 1); stg(0, 2); stg(0, 3);
  stg(1, 0); stg(1, 1); stg(1, 2);
  asm volatile("s_waitcnt vmcnt(6)" ::: "memory");
  __builtin_amdgcn_s_barrier();

  constexpr int NI = NT / 2;
#pragma unroll 1
  for (int u = 0; u < NI - 1; ++u) {
    const int t0 = 2 * u, t1 = t0 + 1;
    phase(t0, IC<0>{}, t1, 3, BC<true>{}, IC<-1>{});
    phase(t0, IC<1>{}, t0 + 2, 0, BC<true>{}, IC<-1>{});
    phase(t0, IC<2>{}, t0 + 2, 1, BC<true>{}, IC<-1>{});
    phase(t0, IC<3>{}, t0 + 2, 2, BC<true>{}, IC<6>{});
    phase(t1, IC<0>{}, t0 + 2, 3, BC<true>{}, IC<-1>{});
    phase(t1, IC<1>{}, t0 + 3, 0, BC<true>{}, IC<-1>{});
    phase(t1, IC<2>{}, t0 + 3, 1, BC<true>{}, IC<-1>{});
    phase(t1, IC<3>{}, t0 + 3, 2, BC<true>{}, IC<6>{});
  }
  {  // tail iteration
    const int t0 = NT - 2, t1 = NT - 1;
    phase(t0, IC<0>{}, t1, 3, BC<true>{}, IC<-1>{});
    phase(t0, IC<1>{}, 0, 0, BC<false>{}, IC<-1>{});
    phase(t0, IC<2>{}, 0, 0, BC<false>{}, IC<-1>{});
    phase(t0, IC<3>{}, 0, 0, BC<false>{}, IC<0>{});
    phase(t1, IC<0>{}, 0, 0, BC<false>{}, IC<-1>{});
    phase(t1, IC<1>{}, 0, 0, BC<false>{}, IC<-1>{});
    phase(t1, IC<2>{}, 0, 0, BC<false>{}, IC<-1>{});
    phase(t1, IC<3>{}, 0, 0, BC<false>{}, IC<-1>{});
  }
}

// ======================= kloop128: BM=256 x BN=128, BK=64 ==================
// 8 waves 4M x 2N; wave tile 64x64. 2 phases per K-tile (phase mh = M-half,
// both k-halves, 16 MFMA). LDS buffer b: A[256][64] at b*24576, B[128][64]
// at +16384. Half-tiles: 0=B full, 1=A 32-row blocks {0,2,4,6} (read at
// mh0), 2=A blocks {1,3,5,7} (read at mh1).
// Steady iter: p0(t0,mh0):(t1,2)  p1(t0,mh1):(t0+2,0)+(t0+2,1)+vmcnt(4)
//              p2(t1,mh0):(t0+2,2) p3(t1,mh1):(t0+3,0)+(t0+3,1)+vmcnt(4)
template <int NT>
__device__ __forceinline__ void kloop128(
    const bf16* __restrict__ Ag, const bf16* __restrict__ Bg, const int KA,
    const int KB, bf16* lds, f32x4 (&acc)[4][4]) {
  const int tid = threadIdx.x;
  const int lane = tid & 63, wave = tid >> 6;
  const int l15 = lane & 15, quad = lane >> 4;
  const int wrow = (wave >> 1) * 64;
  const int wcol = (wave & 1) * 64;
  const int srow = tid >> 3;
  const int scol = ((tid & 7) ^ (srow & 7)) * 8;
  const int swz = l15 & 7;
  const int s5 = srow >> 5;       // wave-uniform
  const int r31 = srow & 31;

  auto stg = [&](int t, int h) {
    bf16* base = lds + (t & 1) * 24576;
    if (h == 0) {            // B rows 0-127
      const bf16* g = Bg + (size_t)srow * KB + t * 64 + scol;
      g2l16(g, base + 16384 + tid * 8);
      g2l16(g + (size_t)64 * KB, base + 16384 + tid * 8 + 4096);
    } else {                 // A stripes: blocks {0,2,4,6} (h=1) / {1,3,5,7}
      const int r0 = s5 * 64 + ((h == 2) ? 32 : 0) + r31;
      const bf16* g = Ag + (size_t)r0 * KA + t * 64 + scol;
      bf16* d = base + ((h == 2) ? 2048 : 0) + s5 * 4096 + r31 * 64 +
                (tid & 7) * 8;
      g2l16(g, d);
      g2l16(g + (size_t)128 * KA, d + 8192);
    }
  };

  bf16x8 bq[2][4];
  auto phase = [&](int t, auto mhc, int st1, int sh1, int st2, auto dsc,
                   auto vmc) {
    constexpr int mh = decltype(mhc)::value;
    constexpr int ds = decltype(dsc)::value;  // 0 none, 1 one, 2 two stages
    constexpr int vm = decltype(vmc)::value;
    bf16* base = lds + (t & 1) * 24576;
    bf16x8 af[2][2];
#pragma unroll
    for (int i = 0; i < 2; ++i)
#pragma unroll
      for (int ks = 0; ks < 2; ++ks)
        af[i][ks] = *(const bf16x8*)&base[
            (wrow + (2 * mh + i) * 16 + l15) * 64 +
            ((ks * 4 + quad) ^ swz) * 8];
    if constexpr (mh == 0) {
#pragma unroll
      for (int j = 0; j < 4; ++j)
#pragma unroll
        for (int ks = 0; ks < 2; ++ks)
          bq[ks][j] = *(const bf16x8*)&base[16384 +
              (wcol + j * 16 + l15) * 64 + ((ks * 4 + quad) ^ swz) * 8];
    }
    if constexpr (ds >= 1) stg(st1, sh1);
    if constexpr (ds == 2) stg(st2, sh1 + 1);
    __builtin_amdgcn_s_barrier();
    __builtin_amdgcn_s_setprio(1);
#pragma unroll
    for (int ks = 0; ks < 2; ++ks)
#pragma unroll
      for (int i = 0; i < 2; ++i)
#pragma unroll
        for (int j = 0; j < 4; ++j)
          acc[2 * mh + i][j] = __builtin_amdgcn_mfma_f32_16x16x32_bf16(
              af[i][ks], bq[ks][j], acc[2 * mh + i][j], 0, 0, 0);
    __builtin_amdgcn_s_setprio(0);
    asm volatile("s_waitcnt lgkmcnt(0)" ::: "memory");
    waitvm<vm>();
    __builtin_amdgcn_s_barrier();
  };

  // prologue: 5 half-tiles (10 loads); vmcnt(4) -> tile 0 fully landed.
  stg(0, 0); stg(0, 1); stg(0, 2);
  stg(1, 0); stg(1, 1);
  asm volatile("s_waitcnt vmcnt(4)" ::: "memory");
  __builtin_amdgcn_s_barrier();

  constexpr int NI = NT / 2;
#pragma unroll 1
  for (int u = 0; u < NI - 1; ++u) {
    const int t0 = 2 * u, t1 = t0 + 1;
    phase(t0, IC<0>{}, t1, 2, 0, IC<1>{}, IC<-1>{});
    phase(t0, IC<1>{}, t0 + 2, 0, t0 + 2, IC<2>{}, IC<4>{});
    phase(t1, IC<0>{}, t0 + 2, 2, 0, IC<1>{}, IC<-1>{});
    phase(t1, IC<1>{}, t0 + 3, 0, t0 + 3, IC<2>{}, IC<4>{});
  }
  {  // tail iteration
    const int t0 = NT - 2, t1 = NT - 1;
    phase(t0, IC<0>{}, t1, 2, 0, IC<1>{}, IC<-1>{});
    phase(t0, IC<1>{}, 0, 0, 0, IC<0>{}, IC<0>{});
    phase(t1, IC<0>{}, 0, 0, 0, IC<0>{}, IC<-1>{});
    phase(t1, IC<1>{}, 0, 0, 0, IC<0>{}, IC<-1>{});
  }
}

// ---------------- fused QKV GEMM -------------------------------------------
// grid (32, 24): x = m-tile (256 rows), y = which*8 + n-tile (128 cols).
__global__ __launch_bounds__(512, 2) void gemm_qkv(
    const bf16* __restrict__ Xb, const bf16* __restrict__ Wb3,
    const float* __restrict__ bq, const float* __restrict__ bk,
    const float* __restrict__ bv, bf16* __restrict__ QK,
    bf16* __restrict__ Vt) {
  __shared__ __align__(16) bf16 lds[2 * 24576];  // 96 KiB
  // XCD swizzle: 768 blocks, 96 per XCD chunk (3 B-panels L2-resident).
  const int bid = blockIdx.y * 32 + blockIdx.x;
  const int sb = (bid & 7) * 96 + (bid >> 3);
  const int bx = sb & 31, by = sb >> 5;
  const int which = by >> 3;
  const int n0 = (by & 7) * 128;
  const int m0 = bx * 256;
  const bf16* Ag = Xb + (size_t)m0 * 1024;
  const bf16* Bg = Wb3 + (size_t)which * 1048576 + (size_t)n0 * 1024;
  const float* bias = (which == 0) ? bq : ((which == 1) ? bk : bv);

  f32x4 acc[4][4];
#pragma unroll
  for (int i = 0; i < 4; ++i)
#pragma unroll
    for (int j = 0; j < 4; ++j) acc[i][j] = f32x4{0.f, 0.f, 0.f, 0.f};

  kloop128<16>(Ag, Bg, 1024, 1024, lds, acc);

  const int lane = threadIdx.x & 63, wave = threadIdx.x >> 6;
  const int l15 = lane & 15, quad = lane >> 4;
  const int wrow = (wave >> 1) * 64, wcol = (wave & 1) * 64;

  // C/D layout: col = lane&15, row = quad*4 + reg [m89/m91]
  if (which < 2) {
    bf16* C = QK + (size_t)which * (size_t)(8192 * 1024);
#pragma unroll
    for (int i = 0; i < 4; ++i) {
      const int r = m0 + wrow + i * 16 + quad * 4;
#pragma unroll
      for (int j = 0; j < 4; ++j) {
        const int c = n0 + wcol + j * 16 + l15;
        const float bvv = bias[c];
        f32x4 v = acc[i][j];
#pragma unroll
        for (int reg = 0; reg < 4; ++reg)
          C[(size_t)(r + reg) * 1024 + c] = (bf16)(v[reg] + bvv);
      }
    }
  } else {
#pragma unroll
    for (int i = 0; i < 4; ++i) {
      const int r = m0 + wrow + i * 16 + quad * 4;  // b*4096+s
      const int b = r >> 12, s = r & 4095;
#pragma unroll
      for (int j = 0; j < 4; ++j) {
        const int c = n0 + wcol + j * 16 + l15;  // h
        const float bvv = bias[c];
        f32x4 v = acc[i][j];
        bf16x4 o;
#pragma unroll
        for (int reg = 0; reg < 4; ++reg) o[reg] = (bf16)(v[reg] + bvv);
        *(bf16x4*)&Vt[((size_t)(b * 1024 + c)) * 4096 + s] = o;
      }
    }
  }
}

// ---------------- scores GEMM + fused exp/mask/row-sum ---------------------
// P[m,k] = exp(Q[m,:]·K[k,:] / 32) (0 where mask==0), unnormalized.
// grid (32, 16): x = m-tile (256), y = n-tile (256).
__global__ __launch_bounds__(512, 2) void gemm_scores(
    const bf16* __restrict__ Q, const bf16* __restrict__ Kb,
    const int* __restrict__ mask, bf16* __restrict__ P,
    float* __restrict__ row_sum) {
  __shared__ __align__(16) bf16 lds[2 * 32768];  // 128 KiB
  // XCD swizzle: 512 blocks, 64 per XCD chunk (2 K-panels L2-resident).
  const int bid = blockIdx.y * 32 + blockIdx.x;
  const int sb = (bid & 7) * 64 + (bid >> 3);
  const int bx = sb & 31, by = sb >> 5;
  const int m0 = bx * 256;
  const int n0 = by * 256;
  const int batch = m0 >> 12;
  const bf16* Ag = Q + (size_t)m0 * 1024;
  const bf16* Bg = Kb + (size_t)batch * (size_t)(4096 * 1024) +
                   (size_t)n0 * 1024;

  f32x4 acc[8][4];
#pragma unroll
  for (int i = 0; i < 8; ++i)
#pragma unroll
    for (int j = 0; j < 4; ++j) acc[i][j] = f32x4{0.f, 0.f, 0.f, 0.f};

  kloop256<16>(Ag, Bg, 1024, 1024, lds, acc);

  const int lane = threadIdx.x & 63, wave = threadIdx.x >> 6;
  const int l15 = lane & 15, quad = lane >> 4;
  const int wrow = (wave >> 2) * 128, wcol = (wave & 3) * 64;

  // Epilogue: e = exp(score/32) (masked), store bf16, atomic row sums.
#pragma unroll
  for (int i = 0; i < 8; ++i) {
    const int r = m0 + wrow + i * 16 + quad * 4;
    f32x4 rsum = f32x4{0.f, 0.f, 0.f, 0.f};
#pragma unroll
    for (int j = 0; j < 4; ++j) {
      const int c = n0 + wcol + j * 16 + l15;
      f32x4 v = acc[i][j];
#pragma unroll
      for (int reg = 0; reg < 4; ++reg) {
        float e = __expf(v[reg] * 0.03125f);
        if (mask[(size_t)(r + reg) * 4096 + c] == 0) e = 0.f;
        P[(size_t)(r + reg) * 4096 + c] = (bf16)e;
        rsum[reg] += e;
      }
    }
    // reduce across the 16 lanes of the quad (l15 bits 0..3)
#pragma unroll
    for (int off = 1; off < 16; off <<= 1) {
#pragma unroll
      for (int reg = 0; reg < 4; ++reg)
        rsum[reg] += __shfl_xor(rsum[reg], off);
    }
    if (l15 == 0) {
#pragma unroll
      for (int reg = 0; reg < 4; ++reg)
        atomicAdd(&row_sum[r + reg], rsum[reg]);
    }
  }
}

// ---------------- PV GEMM with 1/row_sum epilogue --------------------------
// out[m,h] = (P[m,:]·Vt[h,:]) / row_sum[m].  grid (32, 8).
__global__ __launch_bounds__(512, 2) void gemm_pv(
    const bf16* __restrict__ Pm, const bf16* __restrict__ Vt,
    const float* __restrict__ row_sum, float* __restrict__ C) {
  __shared__ __align__(16) bf16 lds[2 * 24576];  // 96 KiB
  // XCD swizzle: 256 blocks, 32 per XCD chunk (1 V-panel L2-resident).
  const int bid = blockIdx.y * 32 + blockIdx.x;
  const int sb = (bid & 7) * 32 + (bid >> 3);
  const int bx = sb & 31, by = sb >> 5;
  const int m0 = bx * 256;
  const int n0 = by * 128;
  const int batch = m0 >> 12;
  const bf16* Ag = Pm + (size_t)m0 * 4096;
  const bf16* Bg = Vt + ((size_t)batch * 1024 + n0) * 4096;

  f32x4 acc[4][4];
#pragma unroll
  for (int i = 0; i < 4; ++i)
#pragma unroll
    for (int j = 0; j < 4; ++j) acc[i][j] = f32x4{0.f, 0.f, 0.f, 0.f};

  kloop128<64>(Ag, Bg, 4096, 4096, lds, acc);

  const int lane = threadIdx.x & 63, wave = threadIdx.x >> 6;
  const int l15 = lane & 15, quad = lane >> 4;
  const int wrow = (wave >> 1) * 64, wcol = (wave & 1) * 64;

#pragma unroll
  for (int i = 0; i < 4; ++i) {
    const int r = m0 + wrow + i * 16 + quad * 4;
    const f32x4 rs = *(const f32x4*)&row_sum[r];
    f32x4 inv;
#pragma unroll
    for (int reg = 0; reg < 4; ++reg) inv[reg] = 1.0f / rs[reg];
#pragma unroll
    for (int j = 0; j < 4; ++j) {
      const int c = n0 + wcol + j * 16 + l15;
      f32x4 v = acc[i][j];
#pragma unroll
      for (int reg = 0; reg < 4; ++reg)
        C[(size_t)(r + reg) * 1024 + c] = v[reg] * inv[reg];
    }
  }
}

extern "C" void kernel_launch(void* const* d_in, const int* in_sizes, int n_in,
                              void* d_out, int out_size, void* d_ws,
                              size_t ws_size, hipStream_t stream) {
  const float* X   = (const float*)d_in[0];
  const int* mask  = (const int*)d_in[1];
  const float* Wq  = (const float*)d_in[2];
  const float* bq  = (const float*)d_in[3];
  const float* Wk  = (const float*)d_in[4];
  const float* bk  = (const float*)d_in[5];
  const float* Wv  = (const float*)d_in[6];
  const float* bv  = (const float*)d_in[7];
  float* out = (float*)d_out;

  // ws layout (128 MiB): [0,16M) Q  [16M,32M) K  [32M,48M) X_bf
  //   [48M,64M) Vt  [64M,128M) Sc/P (first 6 MiB aliased by W_bf).
  //   row_sum (32 KB) aliases X_bf (dead after gemm_qkv).
  const size_t QKV_ELEMS = (size_t)8192 * 1024;
  bf16* Q    = (bf16*)d_ws;
  bf16* Kb   = Q + QKV_ELEMS;
  bf16* X_bf = Kb + QKV_ELEMS;
  bf16* Vt   = X_bf + QKV_ELEMS;
  bf16* Sc   = Vt + QKV_ELEMS;
  bf16* W_bf = Sc;
  float* row_sum = (float*)X_bf;  // 8192 floats

  cvt_f32_bf16<<<dim3(4096), dim3(256), 0, stream>>>(X, X_bf, 8388608);
  cvt_w3<<<dim3(1536), dim3(256), 0, stream>>>(Wq, Wk, Wv, W_bf);
  gemm_qkv<<<dim3(32, 24), dim3(512), 0, stream>>>(X_bf, W_bf, bq, bk, bv, Q,
                                                   Vt);
  hipMemsetAsync(row_sum, 0, 8192 * sizeof(float), stream);
  // P = exp(QK^T/32) masked, unnormalized; row sums via atomics
  gemm_scores<<<dim3(32, 16), dim3(512), 0, stream>>>(Q, Kb, mask, Sc,
                                                      row_sum);
  // out = (P @ V) / row_sum
  gemm_pv<<<dim3(32, 8), dim3(512), 0, stream>>>(Sc, Vt, row_sum, out);
}